// Round 3
// 506.458 us; speedup vs baseline: 1.0359x; 1.0359x over previous
//
#include <hip/hip_runtime.h>

#define B   32
#define TK  2048
#define N   1024
#define NF4 256   // N/4

// out layout (floats): c_t [B*N] at 0, attn_dist [B*TK] at 32768, coverage_out [B*TK] at 98304
#define OUT_CT   0
#define OUT_ATTN (B * N)
#define OUT_COV  (B * N + B * TK)

#define NSLICE 32           // t-slices for c_t partials
#define TPS    (TK / NSLICE) // 64 t per slice

typedef float v4f __attribute__((ext_vector_type(4)));

__device__ __forceinline__ float hw_exp2(float x) {
    return __builtin_amdgcn_exp2f(x);   // v_exp_f32: D = 2^S0
}

__device__ __forceinline__ float fast_tanh(float x) {
    // tanh(x) = 1 - 2/(exp2(2*log2e*x)+1); stable for all x (saturates to +-1)
    float t = hw_exp2(x * 2.8853900817779268f);
    return 1.0f - 2.0f * __builtin_amdgcn_rcpf(t + 1.0f);
}

__device__ __forceinline__ float wave_reduce_sum(float v) {
#pragma unroll
    for (int off = 32; off > 0; off >>= 1) v += __shfl_xor(v, off, 64);
    return v;
}

// non-temporal float4 load: EF/EO are stream-once, keep them out of L2/L3.
// __builtin_nontemporal_load needs a native clang vector type, not float4 struct.
__device__ __forceinline__ float4 ldnt(const float4* p) {
    v4f v = __builtin_nontemporal_load((const v4f*)p);
    return make_float4(v.x, v.y, v.z, v.w);
}

// Kernel 1: dec_fea[b][n] = sum_k s_t_hat[b][k] * W_dec[n][k] + b_dec[n]
// one wave per (n, group of 4 b). 8192 waves -> 2048 blocks of 256.
__global__ __launch_bounds__(256) void decfea_kernel(
    const float4* __restrict__ S,      // s_t_hat as float4 [B*NF4]
    const float4* __restrict__ W,      // W_dec as float4 [N*NF4]
    const float*  __restrict__ bias,   // b_dec [N]
    float*        __restrict__ dec)    // [B*N]
{
    int w    = blockIdx.x * 4 + (threadIdx.x >> 6);  // 0..8191
    int lane = threadIdx.x & 63;
    int n    = w >> 3;
    int b0   = (w & 7) * 4;

    float4 wr[4];
#pragma unroll
    for (int j = 0; j < 4; ++j) wr[j] = W[n * NF4 + j * 64 + lane];

#pragma unroll
    for (int i = 0; i < 4; ++i) {
        int b = b0 + i;
        float acc = 0.0f;
#pragma unroll
        for (int j = 0; j < 4; ++j) {
            float4 s4 = S[b * NF4 + j * 64 + lane];
            acc += s4.x * wr[j].x + s4.y * wr[j].y + s4.z * wr[j].z + s4.w * wr[j].w;
        }
        acc = wave_reduce_sum(acc);
        if (lane == 0) dec[b * N + n] = acc + bias[n];
    }
}

// Kernel 2: scores[r] = sum_n tanh(EF[r][n] + dec[b][n] + cov[r]*W_c[n]) * v_w[n]
// one wave per TWO consecutive rows (same b) -> DEC/WC/VW loads amortize 2x.
// 32768 waves -> 8192 blocks of 256.
__global__ __launch_bounds__(256) void scores_kernel(
    const float4* __restrict__ EF,    // encoder_feature [B*TK*NF4]
    const float4* __restrict__ DEC,   // dec_fea [B*NF4]
    const float4* __restrict__ WC,    // W_c [NF4]
    const float4* __restrict__ VW,    // v_w [NF4]
    const float*  __restrict__ cov,   // coverage [B*TK]
    float*        __restrict__ scores)
{
    int w    = blockIdx.x * 4 + (threadIdx.x >> 6);  // 0..32767
    int lane = threadIdx.x & 63;
    int r0   = w * 2;                 // rows r0, r0+1 (same b: TK even split)
    int b    = r0 >> 11;              // TK = 2048
    float c0 = cov[r0];
    float c1 = cov[r0 + 1];

    const float4* ef0 = EF + (size_t)r0 * NF4;
    const float4* ef1 = ef0 + NF4;
    const float4* de  = DEC + b * NF4;

    float p0 = 0.0f, p1 = 0.0f;
#pragma unroll
    for (int j = 0; j < 4; ++j) {
        int f = j * 64 + lane;
        float4 e0 = ldnt(ef0 + f);
        float4 e1 = ldnt(ef1 + f);
        float4 d  = de[f];
        float4 wc = WC[f];
        float4 vw = VW[f];
        p0 += fast_tanh(e0.x + d.x + c0 * wc.x) * vw.x;
        p0 += fast_tanh(e0.y + d.y + c0 * wc.y) * vw.y;
        p0 += fast_tanh(e0.z + d.z + c0 * wc.z) * vw.z;
        p0 += fast_tanh(e0.w + d.w + c0 * wc.w) * vw.w;
        p1 += fast_tanh(e1.x + d.x + c1 * wc.x) * vw.x;
        p1 += fast_tanh(e1.y + d.y + c1 * wc.y) * vw.y;
        p1 += fast_tanh(e1.z + d.z + c1 * wc.z) * vw.z;
        p1 += fast_tanh(e1.w + d.w + c1 * wc.w) * vw.w;
    }
    p0 = wave_reduce_sum(p0);
    p1 = wave_reduce_sum(p1);
    if (lane == 0) {
        scores[r0]     = p0;
        scores[r0 + 1] = p1;
    }
}

// Kernel 3: softmax over t per b + mask/renorm/stmt epilogue; writes attn_dist
// and coverage_out directly into d_out. one block per b; each thread 8 t.
__global__ __launch_bounds__(256) void softmax_kernel(
    const float* __restrict__ scores,
    const float* __restrict__ mask,
    const float* __restrict__ stmt,
    const float* __restrict__ coverage,
    float*       __restrict__ out)
{
    int b = blockIdx.x, tid = threadIdx.x;
    __shared__ float red[256];

    float s[8];
    float m = -1e30f;
#pragma unroll
    for (int k = 0; k < 8; ++k) {
        s[k] = scores[b * TK + k * 256 + tid];
        m = fmaxf(m, s[k]);
    }
    red[tid] = m;
    __syncthreads();
    for (int step = 128; step > 0; step >>= 1) {
        if (tid < step) red[tid] = fmaxf(red[tid], red[tid + step]);
        __syncthreads();
    }
    float M = red[0];
    __syncthreads();

    // softmax*mask renormalized == e*mask / sum(e*mask)
    float e[8];
    float loc = 0.0f;
#pragma unroll
    for (int k = 0; k < 8; ++k) {
        int t = k * 256 + tid;
        e[k] = hw_exp2((s[k] - M) * 1.4426950408889634f) * mask[b * TK + t];
        loc += e[k];
    }
    red[tid] = loc;
    __syncthreads();
    for (int step = 128; step > 0; step >>= 1) {
        if (tid < step) red[tid] += red[tid + step];
        __syncthreads();
    }
    float inv = 1.0f / red[0];

#pragma unroll
    for (int k = 0; k < 8; ++k) {
        int t = k * 256 + tid;
        int r = b * TK + t;
        float a = e[k] * inv + stmt[r] * mask[r];
        out[OUT_ATTN + r] = a;
        out[OUT_COV + r]  = coverage[r] + a;
    }
}

// Kernel 4: partial c_t per t-slice, NO atomics: part[s][b][n] = sum_{t in slice} attn*EO
// grid (NSLICE, B) x 256 threads; each thread owns one float4 of n.
__global__ __launch_bounds__(256) void ct_partial_kernel(
    const float4* __restrict__ EO,     // encoder_outputs [B*TK*NF4]
    const float*  __restrict__ attn,   // d_out attn region [B*TK]
    float4*       __restrict__ part)   // [NSLICE*B*NF4]
{
    int s = blockIdx.x;   // 0..NSLICE-1
    int b = blockIdx.y;   // 0..B-1
    int tid = threadIdx.x;

    __shared__ float wbuf[TPS];
    if (tid < TPS) wbuf[tid] = attn[b * TK + s * TPS + tid];
    __syncthreads();

    float4 acc = {0.0f, 0.0f, 0.0f, 0.0f};
    const float4* eo = EO + ((size_t)b * TK + s * TPS) * NF4 + tid;
#pragma unroll 8
    for (int tt = 0; tt < TPS; ++tt) {
        float w  = wbuf[tt];
        float4 v = ldnt(eo + (size_t)tt * NF4);
        acc.x += w * v.x;
        acc.y += w * v.y;
        acc.z += w * v.z;
        acc.w += w * v.w;
    }
    part[((size_t)s * B + b) * NF4 + tid] = acc;
}

// Kernel 5: c_t[b][n] = sum_s part[s][b][n]. 8192 float4 -> 32 blocks of 256.
__global__ __launch_bounds__(256) void ct_reduce_kernel(
    const float4* __restrict__ part,
    float4*       __restrict__ ct)     // d_out c_t region as float4 [B*NF4]
{
    int i = blockIdx.x * 256 + threadIdx.x;   // 0..B*NF4-1
    float4 acc = {0.0f, 0.0f, 0.0f, 0.0f};
#pragma unroll
    for (int s = 0; s < NSLICE; ++s) {
        float4 v = part[(size_t)s * (B * NF4) + i];
        acc.x += v.x;
        acc.y += v.y;
        acc.z += v.z;
        acc.w += v.w;
    }
    ct[i] = acc;
}

extern "C" void kernel_launch(void* const* d_in, const int* in_sizes, int n_in,
                              void* d_out, int out_size, void* d_ws, size_t ws_size,
                              hipStream_t stream) {
    const float* s_t_hat = (const float*)d_in[0];
    const float* EO      = (const float*)d_in[1];
    const float* EF      = (const float*)d_in[2];
    const float* stmt    = (const float*)d_in[3];
    const float* mask    = (const float*)d_in[4];
    const float* cov     = (const float*)d_in[5];
    const float* Wdec    = (const float*)d_in[6];
    const float* bdec    = (const float*)d_in[7];
    const float* vw      = (const float*)d_in[8];
    const float* wc      = (const float*)d_in[9];

    float* out = (float*)d_out;
    float* ws  = (float*)d_ws;
    float* dec    = ws;                    // 32768 floats
    float* scores = ws + B * N;            // 65536 floats
    float* part   = ws + B * N + B * TK;   // NSLICE*B*N = 1048576 floats (4 MB)

    decfea_kernel<<<2048, 256, 0, stream>>>(
        (const float4*)s_t_hat, (const float4*)Wdec, bdec, dec);

    scores_kernel<<<8192, 256, 0, stream>>>(
        (const float4*)EF, (const float4*)dec, (const float4*)wc,
        (const float4*)vw, cov, scores);

    softmax_kernel<<<B, 256, 0, stream>>>(scores, mask, stmt, cov, out);

    ct_partial_kernel<<<dim3(NSLICE, B), 256, 0, stream>>>(
        (const float4*)EO, out + OUT_ATTN, (float4*)part);

    ct_reduce_kernel<<<32, 256, 0, stream>>>(
        (const float4*)part, (float4*)(out + OUT_CT));
}